// Round 19
// baseline (287.394 us; speedup 1.0000x reference)
//
#include <hip/hip_runtime.h>

typedef _Float16 f16;
typedef _Float16 f16x8 __attribute__((ext_vector_type(8)));
typedef _Float16 f16x4v __attribute__((ext_vector_type(4)));
typedef float    f32x4 __attribute__((ext_vector_type(4)));
typedef int      i32x4 __attribute__((ext_vector_type(4)));

#define NROWS 1000000
#define DIN   64
#define DH    128
#define SEGS  250000
#define SPB   64

#define MFMA16(a, b, c) __builtin_amdgcn_mfma_f32_16x16x32_f16((a), (b), (c), 0, 0, 0)

// ---------------------------------------------------------------------------
// k_bounds: row_start[s] = first row r with index[r] >= s  (index sorted).
// ---------------------------------------------------------------------------
__global__ void k_bounds(const int* __restrict__ idx,
                         int* __restrict__ row_start, int N) {
  int r = blockIdx.x * blockDim.x + threadIdx.x;
  if (r >= N) return;
  int cur  = min(max(idx[r], 0), SEGS - 1);
  int prev = (r == 0) ? -1 : min(max(idx[r - 1], 0), SEGS - 1);
  for (int s = prev + 1; s <= cur; ++s) row_start[s] = r;
  if (r == N - 1) {
    for (int s = cur + 1; s <= SEGS; ++s) row_start[s] = N;
  }
}

// ---------------------------------------------------------------------------
// k_pack: W[K][128] f32 -> f16 fragments for mfma_f32_16x16x32_f16.
// Lane l, elem e of frag f = cb*T + t (T=K/32):  k = t*32+(l>>4)*8+e,
// c = cb*16+(l&15).  Serve as B-frags of W and A-frags of W^T.
// ---------------------------------------------------------------------------
__global__ void k_pack(const float* __restrict__ W, f16* __restrict__ out, int K) {
  const int T = K >> 5;
  int i = blockIdx.x * blockDim.x + threadIdx.x;
  if (i >= K * DH) return;
  int e = i & 7, l = (i >> 3) & 63, f = i >> 9;
  int t = f % T, cb = f / T;
  int k = t * 32 + ((l >> 4) << 3) + e;
  int c = cb * 16 + (l & 15);
  out[i] = (f16)W[k * DH + c];
}

__device__ __forceinline__ f16x8 ldfrag(const f16* __restrict__ p, int f, int lane) {
  return *(const f16x8*)(p + (((size_t)f * 64 + lane) << 3));
}

__device__ __forceinline__ f16x8 cvt8(f32x4 u0, f32x4 u1) {
  f16x8 r;
  r[0] = (f16)u0[0]; r[1] = (f16)u0[1]; r[2] = (f16)u0[2]; r[3] = (f16)u0[3];
  r[4] = (f16)u1[0]; r[5] = (f16)u1[1]; r[6] = (f16)u1[2]; r[7] = (f16)u1[3];
  return r;
}

// ---------------------------------------------------------------------------
// k_fused: 8 waves, wave owns 16 channels. 128-row tiles = two 64-row
// subtiles per barrier pair (R13 math per subtile, sub-indexed buffers).
// Two independent dep-chains per region hide LDS latency; finalize split
// across waves 2/3 (LDS atomicAdd resolves the boundary segment).
// ---------------------------------------------------------------------------
__global__ __launch_bounds__(512) void k_fused(
    const float* __restrict__ x, const int* __restrict__ idx,
    const int* __restrict__ row_start,
    const f16* __restrict__ vWp, const f16* __restrict__ vPp,
    const f16* __restrict__ aW0p, const f16* __restrict__ aP0p,
    const f16* __restrict__ aW1p, const f16* __restrict__ voWp,
    const float* __restrict__ vb,  const float* __restrict__ vob,
    const float* __restrict__ vlW, const float* __restrict__ vlb,
    const float* __restrict__ ab0, const float* __restrict__ ab1,
    const float* __restrict__ alW, const float* __restrict__ alb,
    float* __restrict__ out)
{
  __shared__ __align__(16) f16   xb16[2][8192];    // 32 KB x tile dbuf (128 rows, swizzled)
  __shared__ __align__(16) f16   Ash[2][8192];     // 32 KB a1^T B-frags per sub
  __shared__ __align__(16) f16   Hsh[16 * 512];    // 16 KB h bounce (2 slots/wave, reused/sub)
  __shared__ __align__(16) f16   IndSh[2][4096];   // 16 KB indicator frags per sub
  __shared__ __align__(16) int   segsh[2][128];    //  1 KB seg ids (128/tile)
  __shared__ __align__(16) float advp[2][8][64];   //  4 KB adv partials per sub
  __shared__ float advsum_sh[SPB];                 // 256 B
  __shared__ float corr_sh[SPB];                   // 256 B

  const int tid  = threadIdx.x;
  const int wave = tid >> 6, lane = tid & 63;
  const int lg = lane >> 4, lm = lane & 15;
  const int s0 = blockIdx.x * SPB;
  const int send = min(s0 + SPB, SEGS);
  const int rbeg = row_start[s0], rend = row_start[send];

  // staging geometry: 512 threads stage 128 rows; 4 threads/row, 16 f32 each
  const int srow_t = tid >> 2;                     // row within 128-row tile
  const int scp    = (tid & 3) * 2;                // first of 2 f16 16B-chunks
  const int swz0   = ((scp ^ (srow_t & 7)) * 16) + srow_t * 128;
  const int swz1   = (((scp + 1) ^ (srow_t & 7)) * 16) + srow_t * 128;

  // indicator-builder geometry: thread (wave, lane) builds frag `wave` per sub
  const int btgt = (wave & 3) * 16 + lm;
  const int bsrc = (wave >> 2) * 32 + lg * 8;

  // transposed-layout scalars (ch = wave*16 + lg*4 + q)
  float b0r[4], b1r[4], alwr[4];
#pragma unroll
  for (int q = 0; q < 4; ++q) {
    const int ch = wave * 16 + lg * 4 + q;
    b0r[q] = ab0[ch]; b1r[q] = ab1[ch]; alwr[q] = alW[ch];
  }
  const int ccol = wave * 16 + lm;
  const float vbr  = vb[ccol];
  const float vobr = vob[ccol];
  const float vlwr = vlW[ccol];
  const float alb0 = alb[0], vlb0 = vlb[0];

  // persistent K=64 weight fragments (32 VGPR)
  f16x8 bW[2], bP[2], w0t[2], p0t[2];
#pragma unroll
  for (int t = 0; t < 2; ++t) {
    bW [t] = ldfrag(vWp,  wave * 2 + t, lane);
    bP [t] = ldfrag(vPp,  wave * 2 + t, lane);
    w0t[t] = ldfrag(aW0p, wave * 2 + t, lane);
    p0t[t] = ldfrag(aP0p, wave * 2 + t, lane);
  }

  f32x4 agg_c[4];
#pragma unroll
  for (int rf = 0; rf < 4; ++rf) { f32x4 z = {0.f,0.f,0.f,0.f}; agg_c[rf] = z; }

  if (tid < SPB) advsum_sh[tid] = 0.f;

  // ---- prologue: stage tile 0 (128 rows, f32 -> f16 swizzled) + segsh ----
  if (rbeg < rend) {
    const float* src = x + (size_t)min(rbeg + srow_t, NROWS - 1) * DIN + (tid & 3) * 16;
    f32x4 u0 = *(const f32x4*)(src);
    f32x4 u1 = *(const f32x4*)(src + 4);
    f32x4 u2 = *(const f32x4*)(src + 8);
    f32x4 u3 = *(const f32x4*)(src + 12);
    *(f16x8*)((char*)&xb16[0][0] + swz0) = cvt8(u0, u1);
    *(f16x8*)((char*)&xb16[0][0] + swz1) = cvt8(u2, u3);
  }
  if (tid < 128) {
    const int n0 = min(128, rend - rbeg);
    int sr = idx[min(rbeg + tid, NROWS - 1)];
    segsh[0][tid] = (tid < n0 && n0 > 0) ? sr - s0 : -1;
  }
  __syncthreads();

  int par = 0;
  for (int rt = rbeg; rt < rend; rt += 128, par ^= 1) {
    const int nrows = min(128, rend - rt);
    const bool has_next = (rt + 128) < rend;
    const int nrows_next = has_next ? min(128, rend - rt - 128) : 0;

    // (a) idx prefetch for next tile's segsh
    const int seg_raw = idx[min(rt + 128 + tid, NROWS - 1)];

    // (b) next tile's x -> regs (coalesced; latency hidden by phases)
    f32x4 xr0, xr1, xr2, xr3;
    if (has_next) {
      const float* src = x + (size_t)min(rt + 128 + srow_t, NROWS - 1) * DIN + (tid & 3) * 16;
      xr0 = *(const f32x4*)(src);
      xr1 = *(const f32x4*)(src + 4);
      xr2 = *(const f32x4*)(src + 8);
      xr3 = *(const f32x4*)(src + 12);
    }

    // (c) indicator build per sub -> IndSh[sub] (published by B1)
#pragma unroll
    for (int sub = 0; sub < 2; ++sub) {
      const i32x4 sa = *(const i32x4*)&segsh[par][sub * 64 + bsrc];
      const i32x4 sb = *(const i32x4*)&segsh[par][sub * 64 + bsrc + 4];
      f16x8 iv;
#pragma unroll
      for (int e = 0; e < 4; ++e) {
        iv[e]     = (sa[e] == btgt) ? (f16)1.f : (f16)0.f;
        iv[e + 4] = (sb[e] == btgt) ? (f16)1.f : (f16)0.f;
      }
      *(f16x8*)&IndSh[sub][(wave * 64 + lane) * 8] = iv;
    }

    // ---- region 1: per sub, phase V -> hb; phase A' -> Ash[sub], pA[sub] ----
    f16x8 hb[2][2];
    float pA[2][4];
#pragma unroll
    for (int sub = 0; sub < 2; ++sub) {
      // ax for this sub
      f16x8 ax[4][2];
#pragma unroll
      for (int rf = 0; rf < 4; ++rf) {
        const int row = sub * 64 + rf * 16 + lm;
        const int rbase = row * 128;
        const int rsw = row & 7;
#pragma unroll
        for (int t = 0; t < 2; ++t)
          ax[rf][t] = *(const f16x8*)((const char*)&xb16[par][0] +
                                      rbase + ((t * 4 + lg) ^ rsw) * 16);
      }

      // phase V: h = relu(x@vW+vb)+x@vP -> hb[sub] via Hsh bounce
      {
        f32x4 cA[4], cB[4];
#pragma unroll
        for (int rf = 0; rf < 4; ++rf) { f32x4 z = {0.f,0.f,0.f,0.f}; cA[rf] = z; cB[rf] = z; }
#pragma unroll
        for (int t = 0; t < 2; ++t)
#pragma unroll
          for (int rf = 0; rf < 4; ++rf) {
            cA[rf] = MFMA16(ax[rf][t], bW[t], cA[rf]);
            cB[rf] = MFMA16(ax[rf][t], bP[t], cB[rf]);
          }
#pragma unroll
        for (int rf = 0; rf < 4; ++rf) {
          f16x4v hv;
#pragma unroll
          for (int q = 0; q < 4; ++q)
            hv[q] = (f16)(fmaxf(cA[rf][q] + vbr, 0.f) + cB[rf][q]);
          const int laneb = ((rf & 1) * 2 + (lg >> 1)) * 16 + lm;
          const int off = ((wave * 2 + (rf >> 1)) * 64 + laneb) * 8 + (lg & 1) * 4;
          *(f16x4v*)&Hsh[off] = hv;
        }
#pragma unroll
        for (int t = 0; t < 2; ++t)   // wave-private read-back (lgkm-ordered)
          hb[sub][t] = *(const f16x8*)&Hsh[((wave * 2 + t) * 64 + lane) * 8];
      }

      // phase A' (transposed): a1^T -> Ash[sub], pA[sub]
      {
        f32x4 cA2[4], cB2[4];
#pragma unroll
        for (int cfr = 0; cfr < 4; ++cfr) { f32x4 z = {0.f,0.f,0.f,0.f}; cA2[cfr] = z; cB2[cfr] = z; }
#pragma unroll
        for (int t = 0; t < 2; ++t)
#pragma unroll
          for (int cfr = 0; cfr < 4; ++cfr) {
            cA2[cfr] = MFMA16(w0t[t], ax[cfr][t], cA2[cfr]);
            cB2[cfr] = MFMA16(p0t[t], ax[cfr][t], cB2[cfr]);
          }
#pragma unroll
        for (int cfr = 0; cfr < 4; ++cfr) {
          f16x4v av;
          float s = 0.f;
#pragma unroll
          for (int q = 0; q < 4; ++q) {
            float a1 = fmaxf(cA2[cfr][q] + b0r[q], 0.f) + cB2[cfr][q];
            s += a1 * alwr[q];
            av[q] = (f16)a1;
          }
          pA[sub][cfr] = s;
          const int lane_a = lm + 16 * ((wave & 1) * 2 + (lg >> 1));
          const int off = ((cfr * 4 + (wave >> 1)) * 64 + lane_a) * 8 + (lg & 1) * 4;
          *(f16x4v*)&Ash[sub][off] = av;
        }
      }
    }

    // (e) w1 frags: in flight across B1, consumed in GEMM2
    f16x8 w1[4];
#pragma unroll
    for (int t = 0; t < 4; ++t)
      w1[t] = ldfrag(aW1p, wave * 4 + t, lane);

    // B1: LDS-only ordering — raw barrier, lgkmcnt only (vmem stays in flight)
    asm volatile("s_waitcnt lgkmcnt(0)" ::: "memory");
    __builtin_amdgcn_s_barrier();

    // ---- region 2: agg += I @ H (both subs), GEMM2 per sub -> advp[sub] ----
#pragma unroll
    for (int sub = 0; sub < 2; ++sub)
#pragma unroll
      for (int t = 0; t < 2; ++t)
#pragma unroll
        for (int rf = 0; rf < 4; ++rf) {
          const f16x8 ind = *(const f16x8*)&IndSh[sub][((t * 4 + rf) * 64 + lane) * 8];
          agg_c[rf] = MFMA16(ind, hb[sub][t], agg_c[rf]);
        }

#pragma unroll
    for (int sub = 0; sub < 2; ++sub) {
      f32x4 c2[4];
#pragma unroll
      for (int cfr = 0; cfr < 4; ++cfr) { f32x4 z = {0.f,0.f,0.f,0.f}; c2[cfr] = z; }
#pragma unroll
      for (int t = 0; t < 4; ++t)
#pragma unroll
        for (int cfr = 0; cfr < 4; ++cfr) {
          const f16x8 bv = *(const f16x8*)&Ash[sub][((cfr * 4 + t) * 64 + lane) * 8];
          c2[cfr] = MFMA16(w1[t], bv, c2[cfr]);
        }
#pragma unroll
      for (int cfr = 0; cfr < 4; ++cfr) {
        float s = pA[sub][cfr];
#pragma unroll
        for (int q = 0; q < 4; ++q)
          s += fmaxf(c2[cfr][q] + b1r[q], 0.f) * alwr[q];
        s += __shfl_xor(s, 16);
        s += __shfl_xor(s, 32);
        if (lg == 0) advp[sub][wave][cfr * 16 + lm] = s;
      }
    }

    // (f) stage next tile + segsh (safe after B1: all reads of cur tile done)
    if (has_next) {
      *(f16x8*)((char*)&xb16[par ^ 1][0] + swz0) = cvt8(xr0, xr1);
      *(f16x8*)((char*)&xb16[par ^ 1][0] + swz1) = cvt8(xr2, xr3);
    }
    if (tid < 128) segsh[par ^ 1][tid] = (tid < nrows_next) ? seg_raw - s0 : -1;

    __syncthreads();   // B2: stage writes + advp + segsh visible

    // finalize: waves 2 and 3 each scan one subtile (atomicAdd: boundary seg)
    if (wave == 2 || wave == 3) {
      const int sub = wave - 2;
      const int base = sub * 64;
      const int r = lane;
      const int nrs = min(64, max(0, nrows - base));
      const bool valid = r < nrs;
      const int sg = valid ? segsh[par][base + r] : -1;
      float acc = 0.f;
      if (valid) {
        float adv = advp[sub][0][r] + advp[sub][1][r] + advp[sub][2][r] + advp[sub][3][r] +
                    advp[sub][4][r] + advp[sub][5][r] + advp[sub][6][r] + advp[sub][7][r] + alb0;
        out[rt + base + r] = adv;
        acc = adv;
      }
#pragma unroll
      for (int d = 1; d < 64; d <<= 1) {
        float nv = __shfl_down(acc, d);
        int   ns = __shfl_down(sg, d);
        if (r + d < 64 && ns == sg) acc += nv;
      }
      if (valid && (r == 0 || segsh[par][base + r - 1] != sg))
        atomicAdd(&advsum_sh[sg], acc);
    }
  }  // tile loop

  // ---------------- stage 2: segment res_block + value head ----------------
  __syncthreads();
#pragma unroll
  for (int rf = 0; rf < 4; ++rf) {
#pragma unroll
    for (int q = 0; q < 4; ++q)
      Ash[0][((rf * 4 + (wave >> 1)) * 64 +
              ((wave & 1) * 2 + (lm >> 3)) * 16 + (lg * 4 + q)) * 8 + (lm & 7)] =
        (f16)agg_c[rf][q];
  }
  __syncthreads();

  {
    f16x8 bvo[4];
#pragma unroll
    for (int t = 0; t < 4; ++t)
      bvo[t] = ldfrag(voWp, wave * 4 + t, lane);
    f32x4 c3[4];
#pragma unroll
    for (int rf = 0; rf < 4; ++rf) { f32x4 z = {0.f,0.f,0.f,0.f}; c3[rf] = z; }
#pragma unroll
    for (int rf = 0; rf < 4; ++rf)
#pragma unroll
      for (int t = 0; t < 4; ++t) {
        const f16x8 av = *(const f16x8*)&Ash[0][((rf * 4 + t) * 64 + lane) * 8];
        c3[rf] = MFMA16(av, bvo[t], c3[rf]);
      }
    f32x4 p3[4];
#pragma unroll
    for (int rf = 0; rf < 4; ++rf)
#pragma unroll
      for (int q = 0; q < 4; ++q) {
        float h2 = fmaxf(c3[rf][q] + vobr, 0.f) + agg_c[rf][q];
        p3[rf][q] = h2 * vlwr;
      }
#pragma unroll
    for (int m = 1; m <= 8; m <<= 1)
#pragma unroll
      for (int rf = 0; rf < 4; ++rf)
#pragma unroll
        for (int q = 0; q < 4; ++q)
          p3[rf][q] += __shfl_xor(p3[rf][q], m);
    if (lm == 0) {
#pragma unroll
      for (int rf = 0; rf < 4; ++rf)
        *(f32x4*)&advp[0][wave][rf * 16 + lg * 4] = p3[rf];
    }
  }
  __syncthreads();

  if (tid < send - s0) {
    float sv = advp[0][0][tid] + advp[0][1][tid] + advp[0][2][tid] + advp[0][3][tid] +
               advp[0][4][tid] + advp[0][5][tid] + advp[0][6][tid] + advp[0][7][tid] + vlb0;
    int cnt = row_start[s0 + tid + 1] - row_start[s0 + tid];
    corr_sh[tid] = sv - advsum_sh[tid] / (float)max(cnt, 1);
  }
  __syncthreads();

  for (int r = rbeg + tid; r < rend; r += 512) {
    const int s = idx[r];
    out[r] += corr_sh[s - s0];
    out[NROWS + r] = (float)s;
  }
}

extern "C" void kernel_launch(void* const* d_in, const int* in_sizes, int n_in,
                              void* d_out, int out_size, void* d_ws, size_t ws_size,
                              hipStream_t stream) {
  (void)n_in; (void)out_size; (void)ws_size;
  const float* x   = (const float*)d_in[0];
  const int*   idx = (const int*)d_in[1];
  const float* vW  = (const float*)d_in[2];
  const float* vb  = (const float*)d_in[3];
  const float* vP  = (const float*)d_in[4];
  const float* voW = (const float*)d_in[5];
  const float* vob = (const float*)d_in[6];
  const float* vlW = (const float*)d_in[7];
  const float* vlb = (const float*)d_in[8];
  const float* aW0 = (const float*)d_in[9];
  const float* ab0 = (const float*)d_in[10];
  const float* aP0 = (const float*)d_in[11];
  const float* aW1 = (const float*)d_in[12];
  const float* ab1 = (const float*)d_in[13];
  const float* alW = (const float*)d_in[14];
  const float* alb = (const float*)d_in[15];

  const int N = in_sizes[0] / DIN;
  float* out = (float*)d_out;

  int* row_start = (int*)d_ws;                                  // SEGS+1 ints
  char* pkbase = (char*)d_ws + (((SEGS + 1) * 4 + 127) & ~127);
  f16* vWp  = (f16*)pkbase;
  f16* vPp  = vWp  + 8192;
  f16* aW0p = vPp  + 8192;
  f16* aP0p = aW0p + 8192;
  f16* aW1p = aP0p + 8192;
  f16* voWp = aW1p + 16384;

  k_bounds<<<(N + 255) / 256, 256, 0, stream>>>(idx, row_start, N);
  k_pack<<<32, 256, 0, stream>>>(vW,  vWp,  64);
  k_pack<<<32, 256, 0, stream>>>(vP,  vPp,  64);
  k_pack<<<32, 256, 0, stream>>>(aW0, aW0p, 64);
  k_pack<<<32, 256, 0, stream>>>(aP0, aP0p, 64);
  k_pack<<<64, 256, 0, stream>>>(aW1, aW1p, 128);
  k_pack<<<64, 256, 0, stream>>>(voW, voWp, 128);

  const int nblk = (SEGS + SPB - 1) / SPB;
  k_fused<<<nblk, 512, 0, stream>>>(x, idx, row_start,
                                    vWp, vPp, aW0p, aP0p, aW1p, voWp,
                                    vb, vob, vlW, vlb, ab0, ab1, alW, alb,
                                    out);
}

// Round 20
// 263.865 us; speedup vs baseline: 1.0892x; 1.0892x over previous
//
#include <hip/hip_runtime.h>

typedef _Float16 f16;
typedef _Float16 f16x8 __attribute__((ext_vector_type(8)));
typedef _Float16 f16x4v __attribute__((ext_vector_type(4)));
typedef float    f32x4 __attribute__((ext_vector_type(4)));
typedef int      i32x4 __attribute__((ext_vector_type(4)));

#define NROWS 1000000
#define DIN   64
#define DH    128
#define SEGS  250000
#define SPB   64

#define MFMA16(a, b, c) __builtin_amdgcn_mfma_f32_16x16x32_f16((a), (b), (c), 0, 0, 0)

// ---------------------------------------------------------------------------
// k_bounds: row_start[s] = first row r with index[r] >= s  (index sorted).
// ---------------------------------------------------------------------------
__global__ void k_bounds(const int* __restrict__ idx,
                         int* __restrict__ row_start, int N) {
  int r = blockIdx.x * blockDim.x + threadIdx.x;
  if (r >= N) return;
  int cur  = min(max(idx[r], 0), SEGS - 1);
  int prev = (r == 0) ? -1 : min(max(idx[r - 1], 0), SEGS - 1);
  for (int s = prev + 1; s <= cur; ++s) row_start[s] = r;
  if (r == N - 1) {
    for (int s = cur + 1; s <= SEGS; ++s) row_start[s] = N;
  }
}

// ---------------------------------------------------------------------------
// k_pack: W[K][128] f32 -> f16 fragments for mfma_f32_16x16x32_f16.
// Lane l, elem e of frag f = cb*T + t (T=K/32):  k = t*32+(l>>4)*8+e,
// c = cb*16+(l&15).  Serve as B-frags of W and A-frags of W^T.
// ---------------------------------------------------------------------------
__global__ void k_pack(const float* __restrict__ W, f16* __restrict__ out, int K) {
  const int T = K >> 5;
  int i = blockIdx.x * blockDim.x + threadIdx.x;
  if (i >= K * DH) return;
  int e = i & 7, l = (i >> 3) & 63, f = i >> 9;
  int t = f % T, cb = f / T;
  int k = t * 32 + ((l >> 4) << 3) + e;
  int c = cb * 16 + (l & 15);
  out[i] = (f16)W[k * DH + c];
}

__device__ __forceinline__ f16x8 ldfrag(const f16* __restrict__ p, int f, int lane) {
  return *(const f16x8*)(p + (((size_t)f * 64 + lane) << 3));
}

__device__ __forceinline__ f16x8 cvt8(f32x4 u0, f32x4 u1) {
  f16x8 r;
  r[0] = (f16)u0[0]; r[1] = (f16)u0[1]; r[2] = (f16)u0[2]; r[3] = (f16)u0[3];
  r[4] = (f16)u1[0]; r[5] = (f16)u1[1]; r[6] = (f16)u1[2]; r[7] = (f16)u1[3];
  return r;
}

// ---------------------------------------------------------------------------
// k_fused: 8 waves (512 thr), wave owns 16 output channels (gcf = wave).
// Block owns segments [s0, s0+64), rows [row_start[s0], row_start[s0+64)).
// x reg-staged one tile ahead (f32 -> f16 LDS, chunk-XOR swizzle).
// Indicator one-hot built ONCE per tile in IndSh; ind-MFMA after B1.
// (R13 — the measured optimum of this structure family; final kernel.)
// ---------------------------------------------------------------------------
__global__ __launch_bounds__(512) void k_fused(
    const float* __restrict__ x, const int* __restrict__ idx,
    const int* __restrict__ row_start,
    const f16* __restrict__ vWp, const f16* __restrict__ vPp,
    const f16* __restrict__ aW0p, const f16* __restrict__ aP0p,
    const f16* __restrict__ aW1p, const f16* __restrict__ voWp,
    const float* __restrict__ vb,  const float* __restrict__ vob,
    const float* __restrict__ vlW, const float* __restrict__ vlb,
    const float* __restrict__ ab0, const float* __restrict__ ab1,
    const float* __restrict__ alW, const float* __restrict__ alb,
    float* __restrict__ out)
{
  __shared__ __align__(16) f16   xb16[2][4096];    // 16 KB x tile double-buffer (f16, swizzled)
  __shared__ __align__(16) f16   Ash[16 * 512];    // 16 KB a1^T B-frags / stage-2 agg A-frags
  __shared__ __align__(16) f16   Hsh[16 * 512];    // 16 KB h B-frag bounce (2 slots/wave)
  __shared__ __align__(16) f16   IndSh[8 * 512];   //  8 KB indicator A-frags (1 tile)
  __shared__ __align__(16) int   segsh[2][64];     // 512 B
  __shared__ __align__(16) float advp[8][64];      // 2 KB
  __shared__ float advsum_sh[SPB];                 // 256 B
  __shared__ float corr_sh[SPB];                   // 256 B

  const int tid  = threadIdx.x;
  const int wave = tid >> 6, lane = tid & 63;
  const int lg = lane >> 4, lm = lane & 15;
  const int s0 = blockIdx.x * SPB;
  const int send = min(s0 + SPB, SEGS);
  const int rbeg = row_start[s0], rend = row_start[send];

  // staging geometry: 512 threads, thread stages 32B (8 f32 -> 8 f16) of one row
  const int srow_t = tid >> 3;                     // row within tile
  const int sc8    = tid & 7;                      // 16B f16 chunk
  const int swz    = ((sc8 ^ (srow_t & 7)) * 16) + srow_t * 128;

  // indicator-builder geometry: thread (wave, lane) builds frag `wave`
  const int btgt = (wave & 3) * 16 + lm;           // one-hot target seg-slot
  const int bsrc = (wave >> 2) * 32 + lg * 8;      // segsh offset of 8 elems

  // transposed-layout scalars (ch = wave*16 + lg*4 + q)
  float b0r[4], b1r[4], alwr[4];
#pragma unroll
  for (int q = 0; q < 4; ++q) {
    const int ch = wave * 16 + lg * 4 + q;
    b0r[q] = ab0[ch]; b1r[q] = ab1[ch]; alwr[q] = alW[ch];
  }
  // C-layout scalars (ch = wave*16 + lm)
  const int ccol = wave * 16 + lm;
  const float vbr  = vb[ccol];
  const float vobr = vob[ccol];
  const float vlwr = vlW[ccol];
  const float alb0 = alb[0], vlb0 = vlb[0];

  // persistent K=64 weight fragments (32 VGPR)
  f16x8 bW[2], bP[2], w0t[2], p0t[2];
#pragma unroll
  for (int t = 0; t < 2; ++t) {
    bW [t] = ldfrag(vWp,  wave * 2 + t, lane);
    bP [t] = ldfrag(vPp,  wave * 2 + t, lane);
    w0t[t] = ldfrag(aW0p, wave * 2 + t, lane);
    p0t[t] = ldfrag(aP0p, wave * 2 + t, lane);
  }

  f32x4 agg_c[4];
#pragma unroll
  for (int rf = 0; rf < 4; ++rf) { f32x4 z = {0.f,0.f,0.f,0.f}; agg_c[rf] = z; }

  if (tid < SPB) advsum_sh[tid] = 0.f;

  // ---- prologue: stage tile 0 (x f32 -> f16 swizzled LDS) + segsh ----
  if (rbeg < rend) {
    const float* src = x + (size_t)min(rbeg + srow_t, NROWS - 1) * DIN + sc8 * 8;
    f32x4 u0 = *(const f32x4*)(src);
    f32x4 u1 = *(const f32x4*)(src + 4);
    *(f16x8*)((char*)&xb16[0][0] + swz) = cvt8(u0, u1);
  }
  if (tid < 64) {
    const int n0 = min(64, rend - rbeg);
    int sr = idx[min(rbeg + tid, NROWS - 1)];
    segsh[0][tid] = (tid < n0 && n0 > 0) ? sr - s0 : -1;
  }
  __syncthreads();

  int par = 0;
  for (int rt = rbeg; rt < rend; rt += 64, par ^= 1) {
    const int nrows = min(64, rend - rt);
    const bool has_next = (rt + 64) < rend;
    const int nrows_next = has_next ? min(64, rend - rt - 64) : 0;

    // (a) idx prefetch for next tile's segsh
    const int seg_raw = idx[min(rt + 64 + tid, NROWS - 1)];

    // (b) next tile's x -> regs (coalesced; latency hidden by phases)
    f32x4 xr0, xr1;
    if (has_next) {
      const float* src = x + (size_t)min(rt + 64 + srow_t, NROWS - 1) * DIN + sc8 * 8;
      xr0 = *(const f32x4*)(src);
      xr1 = *(const f32x4*)(src + 4);
    }

    // (c) indicator build for CURRENT tile -> IndSh (published by B1)
    {
      const i32x4 sa = *(const i32x4*)&segsh[par][bsrc];
      const i32x4 sb = *(const i32x4*)&segsh[par][bsrc + 4];
      f16x8 iv;
#pragma unroll
      for (int e = 0; e < 4; ++e) {
        iv[e]     = (sa[e] == btgt) ? (f16)1.f : (f16)0.f;
        iv[e + 4] = (sb[e] == btgt) ? (f16)1.f : (f16)0.f;
      }
      *(f16x8*)&IndSh[(wave * 64 + lane) * 8] = iv;
    }

    // (d) current x tile: swizzled f16 LDS -> A/B^T fragments
    f16x8 ax[4][2];
#pragma unroll
    for (int rf = 0; rf < 4; ++rf) {
      const int row = rf * 16 + lm;
      const int rbase = row * 128;
      const int rsw = row & 7;
#pragma unroll
      for (int t = 0; t < 2; ++t)
        ax[rf][t] = *(const f16x8*)((const char*)&xb16[par][0] +
                                    rbase + ((t * 4 + lg) ^ rsw) * 16);
    }

    // ---- phase V: h = relu(x@vW+vb)+x@vP -> hb B-frags via Hsh bounce ----
    f16x8 hb[2];
    {
      f32x4 cA[4], cB[4];
#pragma unroll
      for (int rf = 0; rf < 4; ++rf) { f32x4 z = {0.f,0.f,0.f,0.f}; cA[rf] = z; cB[rf] = z; }
#pragma unroll
      for (int t = 0; t < 2; ++t)
#pragma unroll
        for (int rf = 0; rf < 4; ++rf) {
          cA[rf] = MFMA16(ax[rf][t], bW[t], cA[rf]);
          cB[rf] = MFMA16(ax[rf][t], bP[t], cB[rf]);
        }
#pragma unroll
      for (int rf = 0; rf < 4; ++rf) {
        f16x4v hv;
#pragma unroll
        for (int q = 0; q < 4; ++q)
          hv[q] = (f16)(fmaxf(cA[rf][q] + vbr, 0.f) + cB[rf][q]);
        const int laneb = ((rf & 1) * 2 + (lg >> 1)) * 16 + lm;
        const int off = ((wave * 2 + (rf >> 1)) * 64 + laneb) * 8 + (lg & 1) * 4;
        *(f16x4v*)&Hsh[off] = hv;
      }
#pragma unroll
      for (int t = 0; t < 2; ++t)   // wave-private read-back (lgkm-ordered)
        hb[t] = *(const f16x8*)&Hsh[((wave * 2 + t) * 64 + lane) * 8];
    }

    // ---- phase A' (transposed): a1^T = relu(W0^T@x^T+b0)+P0^T@x^T ----
    float pA[4] = {0.f, 0.f, 0.f, 0.f};
    {
      f32x4 cA2[4], cB2[4];
#pragma unroll
      for (int cfr = 0; cfr < 4; ++cfr) { f32x4 z = {0.f,0.f,0.f,0.f}; cA2[cfr] = z; cB2[cfr] = z; }
#pragma unroll
      for (int t = 0; t < 2; ++t)
#pragma unroll
        for (int cfr = 0; cfr < 4; ++cfr) {
          cA2[cfr] = MFMA16(w0t[t], ax[cfr][t], cA2[cfr]);
          cB2[cfr] = MFMA16(p0t[t], ax[cfr][t], cB2[cfr]);
        }
#pragma unroll
      for (int cfr = 0; cfr < 4; ++cfr) {
        f16x4v av;
#pragma unroll
        for (int q = 0; q < 4; ++q) {
          float a1 = fmaxf(cA2[cfr][q] + b0r[q], 0.f) + cB2[cfr][q];
          pA[cfr] += a1 * alwr[q];
          av[q] = (f16)a1;
        }
        const int lane_a = lm + 16 * ((wave & 1) * 2 + (lg >> 1));
        const int off = ((cfr * 4 + (wave >> 1)) * 64 + lane_a) * 8 + (lg & 1) * 4;
        *(f16x4v*)&Ash[off] = av;
      }
    }

    // (e) w1 frags issued here: in flight across B1, consumed in GEMM2
    f16x8 w1[4];
#pragma unroll
    for (int t = 0; t < 4; ++t)
      w1[t] = ldfrag(aW1p, wave * 4 + t, lane);

    // B1: LDS-only ordering — raw barrier, lgkmcnt only (loads stay in flight)
    asm volatile("s_waitcnt lgkmcnt(0)" ::: "memory");
    __builtin_amdgcn_s_barrier();

    // ---- agg += I @ H  (indicator frags from IndSh, shared across waves) ----
#pragma unroll
    for (int t = 0; t < 2; ++t)
#pragma unroll
      for (int rf = 0; rf < 4; ++rf) {
        const f16x8 ind = *(const f16x8*)&IndSh[((t * 4 + rf) * 64 + lane) * 8];
        agg_c[rf] = MFMA16(ind, hb[t], agg_c[rf]);
      }

    // ---- GEMM2^T: relu(W1^T@a1^T+b1)·alW (+pA) -> per-row adv partials ----
    {
      f32x4 c2[4];
#pragma unroll
      for (int cfr = 0; cfr < 4; ++cfr) { f32x4 z = {0.f,0.f,0.f,0.f}; c2[cfr] = z; }
#pragma unroll
      for (int t = 0; t < 4; ++t)
#pragma unroll
        for (int cfr = 0; cfr < 4; ++cfr) {
          const f16x8 bv = *(const f16x8*)&Ash[((cfr * 4 + t) * 64 + lane) * 8];
          c2[cfr] = MFMA16(w1[t], bv, c2[cfr]);
        }
#pragma unroll
      for (int cfr = 0; cfr < 4; ++cfr) {
        float s = pA[cfr];
#pragma unroll
        for (int q = 0; q < 4; ++q)
          s += fmaxf(c2[cfr][q] + b1r[q], 0.f) * alwr[q];
        s += __shfl_xor(s, 16);
        s += __shfl_xor(s, 32);
        if (lg == 0) advp[wave][cfr * 16 + lm] = s;
      }
    }

    // (f) stage next tile + segsh (safe after B1: all reads of cur tile done)
    if (has_next)
      *(f16x8*)((char*)&xb16[par ^ 1][0] + swz) = cvt8(xr0, xr1);
    if (tid < 64) segsh[par ^ 1][tid] = (tid < nrows_next) ? seg_raw - s0 : -1;

    __syncthreads();   // B2: stage writes + advp + segsh visible

    if (wave == 2) {   // finalize: adv out + segmented suffix scan -> advsum
      const int r = lane;
      const bool valid = r < nrows;
      const int sg = valid ? segsh[par][r] : -1;
      float acc = 0.f;
      if (valid) {
        float adv = advp[0][r] + advp[1][r] + advp[2][r] + advp[3][r] +
                    advp[4][r] + advp[5][r] + advp[6][r] + advp[7][r] + alb0;
        out[rt + r] = adv;
        acc = adv;
      }
#pragma unroll
      for (int d = 1; d < 64; d <<= 1) {
        float nv = __shfl_down(acc, d);
        int   ns = __shfl_down(sg, d);
        if (r + d < 64 && ns == sg) acc += nv;
      }
      if (valid && (r == 0 || segsh[par][r - 1] != sg)) advsum_sh[sg] += acc;
    }
  }  // tile loop

  // ---------------- stage 2: segment res_block + value head ----------------
  __syncthreads();
#pragma unroll
  for (int rf = 0; rf < 4; ++rf) {
#pragma unroll
    for (int q = 0; q < 4; ++q)
      Ash[((rf * 4 + (wave >> 1)) * 64 +
           ((wave & 1) * 2 + (lm >> 3)) * 16 + (lg * 4 + q)) * 8 + (lm & 7)] =
        (f16)agg_c[rf][q];
  }
  __syncthreads();

  {
    f16x8 bvo[4];
#pragma unroll
    for (int t = 0; t < 4; ++t)
      bvo[t] = ldfrag(voWp, wave * 4 + t, lane);
    f32x4 c3[4];
#pragma unroll
    for (int rf = 0; rf < 4; ++rf) { f32x4 z = {0.f,0.f,0.f,0.f}; c3[rf] = z; }
#pragma unroll
    for (int rf = 0; rf < 4; ++rf)
#pragma unroll
      for (int t = 0; t < 4; ++t) {
        const f16x8 av = *(const f16x8*)&Ash[((rf * 4 + t) * 64 + lane) * 8];
        c3[rf] = MFMA16(av, bvo[t], c3[rf]);
      }
    f32x4 p3[4];
#pragma unroll
    for (int rf = 0; rf < 4; ++rf)
#pragma unroll
      for (int q = 0; q < 4; ++q) {
        float h2 = fmaxf(c3[rf][q] + vobr, 0.f) + agg_c[rf][q];
        p3[rf][q] = h2 * vlwr;
      }
#pragma unroll
    for (int m = 1; m <= 8; m <<= 1)
#pragma unroll
      for (int rf = 0; rf < 4; ++rf)
#pragma unroll
        for (int q = 0; q < 4; ++q)
          p3[rf][q] += __shfl_xor(p3[rf][q], m);
    if (lm == 0) {
#pragma unroll
      for (int rf = 0; rf < 4; ++rf)
        *(f32x4*)&advp[wave][rf * 16 + lg * 4] = p3[rf];
    }
  }
  __syncthreads();

  if (tid < send - s0) {
    float sv = advp[0][tid] + advp[1][tid] + advp[2][tid] + advp[3][tid] +
               advp[4][tid] + advp[5][tid] + advp[6][tid] + advp[7][tid] + vlb0;
    int cnt = row_start[s0 + tid + 1] - row_start[s0 + tid];
    corr_sh[tid] = sv - advsum_sh[tid] / (float)max(cnt, 1);
  }
  __syncthreads();

  for (int r = rbeg + tid; r < rend; r += 512) {
    const int s = idx[r];
    out[r] += corr_sh[s - s0];
    out[NROWS + r] = (float)s;
  }
}

extern "C" void kernel_launch(void* const* d_in, const int* in_sizes, int n_in,
                              void* d_out, int out_size, void* d_ws, size_t ws_size,
                              hipStream_t stream) {
  (void)n_in; (void)out_size; (void)ws_size;
  const float* x   = (const float*)d_in[0];
  const int*   idx = (const int*)d_in[1];
  const float* vW  = (const float*)d_in[2];
  const float* vb  = (const float*)d_in[3];
  const float* vP  = (const float*)d_in[4];
  const float* voW = (const float*)d_in[5];
  const float* vob = (const float*)d_in[6];
  const float* vlW = (const float*)d_in[7];
  const float* vlb = (const float*)d_in[8];
  const float* aW0 = (const float*)d_in[9];
  const float* ab0 = (const float*)d_in[10];
  const float* aP0 = (const float*)d_in[11];
  const float* aW1 = (const float*)d_in[12];
  const float* ab1 = (const float*)d_in[13];
  const float* alW = (const float*)d_in[14];
  const float* alb = (const float*)d_in[15];

  const int N = in_sizes[0] / DIN;
  float* out = (float*)d_out;

  int* row_start = (int*)d_ws;                                  // SEGS+1 ints
  char* pkbase = (char*)d_ws + (((SEGS + 1) * 4 + 127) & ~127);
  f16* vWp  = (f16*)pkbase;
  f16* vPp  = vWp  + 8192;
  f16* aW0p = vPp  + 8192;
  f16* aP0p = aW0p + 8192;
  f16* aW1p = aP0p + 8192;
  f16* voWp = aW1p + 16384;

  k_bounds<<<(N + 255) / 256, 256, 0, stream>>>(idx, row_start, N);
  k_pack<<<32, 256, 0, stream>>>(vW,  vWp,  64);
  k_pack<<<32, 256, 0, stream>>>(vP,  vPp,  64);
  k_pack<<<32, 256, 0, stream>>>(aW0, aW0p, 64);
  k_pack<<<32, 256, 0, stream>>>(aP0, aP0p, 64);
  k_pack<<<64, 256, 0, stream>>>(aW1, aW1p, 128);
  k_pack<<<64, 256, 0, stream>>>(voW, voWp, 128);

  const int nblk = (SEGS + SPB - 1) / SPB;
  k_fused<<<nblk, 512, 0, stream>>>(x, idx, row_start,
                                    vWp, vPp, aW0p, aP0p, aW1p, voWp,
                                    vb, vob, vlW, vlb, ab0, ab1, alW, alb,
                                    out);
}